// Round 6
// baseline (85.017 us; speedup 1.0000x reference)
//
#include <hip/hip_runtime.h>
#include <hip/hip_bf16.h>

// QueryGrouper: ball_query (first-K-in-index-order within radius) + grouping.
// B=4, N=8192, M=2048, C=128, K=32, radius=0.1, use_xyz from out_size.
//
// R6: decoupled gather. R2/R3/R5 all plateaued ~70us: the per-iteration
// idx-load wait (ordered vmcnt) had to drain the prior iteration's stores
// under full HBM write pressure. Fix: ALL idx prefetched to registers before
// the first store; store phase has no global loads at all.
// Block = (channel-pair, batch, m-quarter): 1024 blocks x 1024 thr, 64KB LDS
// (both channel rows, contiguous in feat -> linear float4 stage), 2 blocks/CU.

#define K_NEIGH 32
// f32(0.010000000000000002) — matches JAX weak-typed radius*radius bit-exactly.
#define R2_F32 0.009999999776482582f
#define CCH 128
#define NPTS 8192
#define MQ 2048

typedef float f32x2 __attribute__((ext_vector_type(2)));

__global__ __launch_bounds__(256) void ball_query_xyz_kernel(
    const float* __restrict__ xyz,      // (B,3,N)
    const float* __restrict__ new_xyz,  // (B,3,M)
    int* __restrict__ idxb,             // (B*M, K)
    float* __restrict__ out0,           // (B, CO, M, K)
    float* __restrict__ out1,           // (B, 3, M, K)
    int N, int M, int C, int use_xyz)
{
    __shared__ int lidx[4][K_NEIGH];
    const int wave = threadIdx.x >> 6;
    const int lane = threadIdx.x & 63;
    const int q = blockIdx.x * 4 + wave;           // query id in [0, B*M)
    const int b = q / M;
    const int m = q - b * M;

    const float* xb = xyz + (size_t)b * 3 * N;
    const float* nb = new_xyz + (size_t)b * 3 * M;
    const float qx = nb[m];
    const float qy = nb[M + m];
    const float qz = nb[2 * M + m];

    int cnt = 0;
    int first_found = 0;   // pad value: first in-ball index, or 0 if none

    for (int t0 = 0; t0 < N; t0 += 64) {
        const int i = t0 + lane;
        // match JAX: sub, square (no FMA), left-to-right sum, all f32 RN
        const float dx = xb[i]         - qx;
        const float dy = xb[N + i]     - qy;
        const float dz = xb[2 * N + i] - qz;
        const float d2 = __fadd_rn(__fadd_rn(__fmul_rn(dx, dx), __fmul_rn(dy, dy)),
                                   __fmul_rn(dz, dz));
        const bool in_ball = d2 < R2_F32;
        const unsigned long long mask = __ballot(in_ball);
        if (mask) {
            if (cnt == 0) {
                first_found = t0 + (__ffsll((unsigned long long)mask) - 1);
            }
            if (in_ball) {
                const int pos = cnt + __popcll(mask & ((1ull << lane) - 1ull));
                if (pos < K_NEIGH) lidx[wave][pos] = i;
            }
            cnt += __popcll(mask);
            if (cnt >= K_NEIGH) break;   // first K found (in index order)
        }
    }

    // make this wave's LDS writes visible to its own lanes
    asm volatile("s_waitcnt lgkmcnt(0)" ::: "memory");

    if (lane < K_NEIGH) {
        const int j = (lane < cnt) ? lidx[wave][lane] : first_found;
        idxb[(size_t)q * K_NEIGH + lane] = j;
        const float gx = xb[j]         - qx;
        const float gy = xb[N + j]     - qy;
        const float gz = xb[2 * N + j] - qz;
        const size_t MK = (size_t)M * K_NEIGH;
        const size_t o1 = (size_t)b * 3 * MK + (size_t)m * K_NEIGH + lane;
        out1[o1]          = gx;
        out1[o1 + MK]     = gy;
        out1[o1 + 2 * MK] = gz;
        if (use_xyz) {
            const size_t o0 = (size_t)b * (C + 3) * MK + (size_t)m * K_NEIGH + lane;
            out0[o0]          = gx;
            out0[o0 + MK]     = gy;
            out0[o0 + 2 * MK] = gz;
        }
    }
}

// Fixed geometry: B=4, N=8192, M=2048, C=128.
// grid = 1024: slab = bid & 15 -> (b, m-quarter); cg = bid >> 4 (channel pair).
// Same-slab blocks have equal bid%8 -> same XCD: 64KB idx slab stays L2-hot.
// Phase A: 8 int2 idx -> regs, 64KB feat (rows c0,c0+1 contiguous) -> LDS.
// Phase B: per pair-item 4x ds_read_b32 + 2x f32x2 store; NO global loads.
__global__ __launch_bounds__(1024, 8) void gather_chan3_kernel(
    const float* __restrict__ feat,  // (B,C,N)
    const int* __restrict__ idxb,    // (B*M,K)
    float* __restrict__ out0,        // (B,CO,M,K)
    int use_xyz)
{
    __shared__ float sf[2 * NPTS];   // 64 KB: [0,N) = ch c0, [N,2N) = ch c0+1

    const int t    = threadIdx.x;
    const int bid  = blockIdx.x;
    const int slab = bid & 15;         // b*4 + mq
    const int cg   = bid >> 4;         // 0..63
    const int b    = slab >> 2;
    const int mq   = slab & 3;
    const int c0   = cg * 2;
    const int m0   = mq * (MQ / 4);    // 512-query quarter

    // ---- Phase A: idx prefetch (regs) + feat stage (LDS) ----
    const int2* ip2 = (const int2*)(idxb + ((size_t)b * MQ + m0) * K_NEIGH);
    int2 jj[8];
    #pragma unroll
    for (int i = 0; i < 8; ++i) jj[i] = ip2[i * 1024 + t];

    const float4* fv = (const float4*)(feat + ((size_t)b * CCH + c0) * NPTS);
    #pragma unroll
    for (int r = 0; r < 4; ++r) {
        const int i = t + r * 1024;          // 4096 float4 = both rows
        ((float4*)sf)[i] = fv[i];
    }
    __syncthreads();

    // ---- Phase B: pure LDS-read + store ----
    const size_t MK = (size_t)MQ * K_NEIGH;
    const int CO   = use_xyz ? (CCH + 3) : CCH;
    const int coff = use_xyz ? 3 : 0;
    float* o0 = out0 + ((size_t)b * CO + coff + c0) * MK + (size_t)m0 * K_NEIGH;
    float* o1 = o0 + MK;

    #pragma unroll
    for (int i = 0; i < 8; ++i) {
        const int p  = i * 2048 + 2 * t;     // flat (m_local,k) pair position
        const int ja = jj[i].x;
        const int jb = jj[i].y;
        f32x2 s0; s0.x = sf[ja];        s0.y = sf[jb];
        f32x2 s1; s1.x = sf[NPTS + ja]; s1.y = sf[NPTS + jb];
        *(f32x2*)(o0 + p) = s0;
        *(f32x2*)(o1 + p) = s1;
    }
}

// Fallback gather (any shape): R1 structure.
__global__ __launch_bounds__(256) void gather_kernel(
    const float* __restrict__ xyz, const float* __restrict__ new_xyz,
    const float* __restrict__ feat, const int* __restrict__ idxb,
    float* __restrict__ out0, float* __restrict__ out1,
    int N, int M, int C, int use_xyz)
{
    const int tid = threadIdx.x;
    const int k = tid & 31;
    const int mloc = tid >> 5;
    const int mchunks = M >> 3;
    const int b = blockIdx.x / mchunks;
    const int m = (blockIdx.x - b * mchunks) * 8 + mloc;
    const int q = b * M + m;
    const int j = idxb[(size_t)q * K_NEIGH + k];
    const size_t xb = (size_t)b * 3 * N;
    const size_t nb = (size_t)b * 3 * M;
    const float gx = xyz[xb + j]         - new_xyz[nb + m];
    const float gy = xyz[xb + N + j]     - new_xyz[nb + M + m];
    const float gz = xyz[xb + 2 * N + j] - new_xyz[nb + 2 * M + m];
    const size_t MK = (size_t)M * K_NEIGH;
    const size_t o1 = (size_t)b * 3 * MK + (size_t)m * K_NEIGH + k;
    out1[o1] = gx; out1[o1 + MK] = gy; out1[o1 + 2 * MK] = gz;
    const int CO = use_xyz ? (C + 3) : C;
    size_t o0 = (size_t)b * CO * MK + (size_t)m * K_NEIGH + k;
    if (use_xyz) {
        out0[o0] = gx; out0[o0 + MK] = gy; out0[o0 + 2 * MK] = gz;
        o0 += 3 * MK;
    }
    const float* fb = feat + (size_t)b * C * N;
    #pragma unroll 4
    for (int c = 0; c < C; c += 4) {
        const float v0 = fb[(size_t)c * N + j];
        const float v1 = fb[(size_t)(c + 1) * N + j];
        const float v2 = fb[(size_t)(c + 2) * N + j];
        const float v3 = fb[(size_t)(c + 3) * N + j];
        out0[o0 + (size_t)c * MK]       = v0;
        out0[o0 + (size_t)(c + 1) * MK] = v1;
        out0[o0 + (size_t)(c + 2) * MK] = v2;
        out0[o0 + (size_t)(c + 3) * MK] = v3;
    }
}

extern "C" void kernel_launch(void* const* d_in, const int* in_sizes, int n_in,
                              void* d_out, int out_size, void* d_ws, size_t ws_size,
                              hipStream_t stream) {
    const float* new_xyz = (const float*)d_in[0];   // (B,3,M)
    const float* xyz     = (const float*)d_in[1];   // (B,3,N)
    const float* feat    = (const float*)d_in[2];   // (B,C,N)

    const int B = 4;                       // fixed by harness setup
    const int M = in_sizes[0] / (3 * B);   // 2048
    const int N = in_sizes[1] / (3 * B);   // 8192
    const int C = in_sizes[2] / (B * N);   // 128

    const long long sz_with = (long long)B * (C + 6) * M * K_NEIGH;
    const int use_xyz = (out_size == sz_with) ? 1 : 0;

    float* out0 = (float*)d_out;
    float* out1 = out0 + (size_t)B * (use_xyz ? (C + 3) : C) * M * K_NEIGH;

    int* idxb = (int*)d_ws;  // B*M*K ints = 1 MB
    const size_t idx_bytes = (size_t)B * M * K_NEIGH * sizeof(int);

    const bool fast = (B == 4) && (N == NPTS) && (M == MQ) && (C == CCH)
                      && (ws_size >= idx_bytes);

    ball_query_xyz_kernel<<<(B * M) / 4, 256, 0, stream>>>(
        xyz, new_xyz, idxb, out0, out1, N, M, C, use_xyz);

    if (fast) {
        gather_chan3_kernel<<<1024, 1024, 0, stream>>>(feat, idxb, out0, use_xyz);
    } else {
        gather_kernel<<<B * (M / 8), 256, 0, stream>>>(xyz, new_xyz, feat, idxb,
                                                       out0, out1, N, M, C, use_xyz);
    }
}

// Round 7
// 76.881 us; speedup vs baseline: 1.1058x; 1.1058x over previous
//
#include <hip/hip_runtime.h>
#include <hip/hip_bf16.h>

// QueryGrouper: ball_query (first-K-in-index-order within radius) + grouping.
// B=4, N=8192, M=2048, C=128, K=32, radius=0.1, use_xyz from out_size.
//
// R7: ONE-PASS staged gather. R2..R6 all plateaued 66-77us with >=2x feat
// staging amplification; hypothesis: HBM read/write turnaround + L2 thrash
// from interleaving staging re-reads with the 134MB write stream. Fix: block
// = (channel-pair, batch), grid 256 (1/CU), each feat byte read ONCE from HBM
// (16.8MB cold), idx b-slab XCD-pinned (L2-hot), all idx prefetched to regs.
// HBM profile becomes ~19MB reads + 141MB writes ~= pure write stream.

#define K_NEIGH 32
// f32(0.010000000000000002) — matches JAX weak-typed radius*radius bit-exactly.
#define R2_F32 0.009999999776482582f
#define CCH 128
#define NPTS 8192
#define MQ 2048

typedef float f32x2 __attribute__((ext_vector_type(2)));

__global__ __launch_bounds__(256) void ball_query_xyz_kernel(
    const float* __restrict__ xyz,      // (B,3,N)
    const float* __restrict__ new_xyz,  // (B,3,M)
    int* __restrict__ idxb,             // (B*M, K)
    float* __restrict__ out0,           // (B, CO, M, K)
    float* __restrict__ out1,           // (B, 3, M, K)
    int N, int M, int C, int use_xyz)
{
    __shared__ int lidx[4][K_NEIGH];
    const int wave = threadIdx.x >> 6;
    const int lane = threadIdx.x & 63;
    const int q = blockIdx.x * 4 + wave;           // query id in [0, B*M)
    const int b = q / M;
    const int m = q - b * M;

    const float* xb = xyz + (size_t)b * 3 * N;
    const float* nb = new_xyz + (size_t)b * 3 * M;
    const float qx = nb[m];
    const float qy = nb[M + m];
    const float qz = nb[2 * M + m];

    int cnt = 0;
    int first_found = 0;   // pad value: first in-ball index, or 0 if none

    for (int t0 = 0; t0 < N; t0 += 64) {
        const int i = t0 + lane;
        // match JAX: sub, square (no FMA), left-to-right sum, all f32 RN
        const float dx = xb[i]         - qx;
        const float dy = xb[N + i]     - qy;
        const float dz = xb[2 * N + i] - qz;
        const float d2 = __fadd_rn(__fadd_rn(__fmul_rn(dx, dx), __fmul_rn(dy, dy)),
                                   __fmul_rn(dz, dz));
        const bool in_ball = d2 < R2_F32;
        const unsigned long long mask = __ballot(in_ball);
        if (mask) {
            if (cnt == 0) {
                first_found = t0 + (__ffsll((unsigned long long)mask) - 1);
            }
            if (in_ball) {
                const int pos = cnt + __popcll(mask & ((1ull << lane) - 1ull));
                if (pos < K_NEIGH) lidx[wave][pos] = i;
            }
            cnt += __popcll(mask);
            if (cnt >= K_NEIGH) break;   // first K found (in index order)
        }
    }

    // make this wave's LDS writes visible to its own lanes
    asm volatile("s_waitcnt lgkmcnt(0)" ::: "memory");

    if (lane < K_NEIGH) {
        const int j = (lane < cnt) ? lidx[wave][lane] : first_found;
        idxb[(size_t)q * K_NEIGH + lane] = j;
        const float gx = xb[j]         - qx;
        const float gy = xb[N + j]     - qy;
        const float gz = xb[2 * N + j] - qz;
        const size_t MK = (size_t)M * K_NEIGH;
        const size_t o1 = (size_t)b * 3 * MK + (size_t)m * K_NEIGH + lane;
        out1[o1]          = gx;
        out1[o1 + MK]     = gy;
        out1[o1 + 2 * MK] = gz;
        if (use_xyz) {
            const size_t o0 = (size_t)b * (C + 3) * MK + (size_t)m * K_NEIGH + lane;
            out0[o0]          = gx;
            out0[o0 + MK]     = gy;
            out0[o0 + 2 * MK] = gz;
        }
    }
}

// Fixed geometry: B=4, N=8192, M=2048, C=128. Grid = 256 blocks x 1024 thr.
// bid -> b = (bid&7)>>1 (XCD-pinned: 2 XCDs per batch -> idx slab L2-hot),
// cg = ((bid>>3)<<1)|(bid&1). Each block: stage 64KB feat slab ONCE, prefetch
// all 64 idx to regs (32x int2), then pure LDS-read + coalesced f32x2 stores
// over all 2048 queries. No global loads after the first store.
__global__ __launch_bounds__(1024, 4) void gather_onepass_kernel(
    const float* __restrict__ feat,  // (B,C,N)
    const int* __restrict__ idxb,    // (B*M,K)
    float* __restrict__ out0,        // (B,CO,M,K)
    int use_xyz)
{
    __shared__ float sf[2 * NPTS];   // 64 KB: [0,N) = ch c0, [N,2N) = ch c0+1

    const int t   = threadIdx.x;
    const int bid = blockIdx.x;
    const int b   = (bid & 7) >> 1;                 // 0..3, pinned per XCD pair
    const int cg  = ((bid >> 3) << 1) | (bid & 1);  // 0..63
    const int c0  = cg * 2;

    // ---- Phase A: all loads issued before any store ----
    const int2* ip2 = (const int2*)(idxb + (size_t)b * MQ * K_NEIGH);
    int2 jj[32];
    #pragma unroll
    for (int i = 0; i < 32; ++i) jj[i] = ip2[i * 1024 + t];

    const float4* fv = (const float4*)(feat + ((size_t)b * CCH + c0) * NPTS);
    #pragma unroll
    for (int r = 0; r < 4; ++r)
        ((float4*)sf)[t + r * 1024] = fv[t + r * 1024];
    __syncthreads();

    // ---- Phase B: pure LDS-read + store, all 2048 queries ----
    const size_t MK = (size_t)MQ * K_NEIGH;
    const int CO   = use_xyz ? (CCH + 3) : CCH;
    const int coff = use_xyz ? 3 : 0;
    float* o0 = out0 + ((size_t)b * CO + coff + c0) * MK;
    float* o1 = o0 + MK;

    #pragma unroll
    for (int i = 0; i < 32; ++i) {
        const int p  = (i * 1024 + t) * 2;   // flat (m,k) pair position
        const int ja = jj[i].x;
        const int jb = jj[i].y;
        f32x2 s0; s0.x = sf[ja];        s0.y = sf[jb];
        f32x2 s1; s1.x = sf[NPTS + ja]; s1.y = sf[NPTS + jb];
        *(f32x2*)(o0 + p) = s0;
        *(f32x2*)(o1 + p) = s1;
    }
}

// Fallback gather (any shape): R1 structure.
__global__ __launch_bounds__(256) void gather_kernel(
    const float* __restrict__ xyz, const float* __restrict__ new_xyz,
    const float* __restrict__ feat, const int* __restrict__ idxb,
    float* __restrict__ out0, float* __restrict__ out1,
    int N, int M, int C, int use_xyz)
{
    const int tid = threadIdx.x;
    const int k = tid & 31;
    const int mloc = tid >> 5;
    const int mchunks = M >> 3;
    const int b = blockIdx.x / mchunks;
    const int m = (blockIdx.x - b * mchunks) * 8 + mloc;
    const int q = b * M + m;
    const int j = idxb[(size_t)q * K_NEIGH + k];
    const size_t xb = (size_t)b * 3 * N;
    const size_t nb = (size_t)b * 3 * M;
    const float gx = xyz[xb + j]         - new_xyz[nb + m];
    const float gy = xyz[xb + N + j]     - new_xyz[nb + M + m];
    const float gz = xyz[xb + 2 * N + j] - new_xyz[nb + 2 * M + m];
    const size_t MK = (size_t)M * K_NEIGH;
    const size_t o1 = (size_t)b * 3 * MK + (size_t)m * K_NEIGH + k;
    out1[o1] = gx; out1[o1 + MK] = gy; out1[o1 + 2 * MK] = gz;
    const int CO = use_xyz ? (C + 3) : C;
    size_t o0 = (size_t)b * CO * MK + (size_t)m * K_NEIGH + k;
    if (use_xyz) {
        out0[o0] = gx; out0[o0 + MK] = gy; out0[o0 + 2 * MK] = gz;
        o0 += 3 * MK;
    }
    const float* fb = feat + (size_t)b * C * N;
    #pragma unroll 4
    for (int c = 0; c < C; c += 4) {
        const float v0 = fb[(size_t)c * N + j];
        const float v1 = fb[(size_t)(c + 1) * N + j];
        const float v2 = fb[(size_t)(c + 2) * N + j];
        const float v3 = fb[(size_t)(c + 3) * N + j];
        out0[o0 + (size_t)c * MK]       = v0;
        out0[o0 + (size_t)(c + 1) * MK] = v1;
        out0[o0 + (size_t)(c + 2) * MK] = v2;
        out0[o0 + (size_t)(c + 3) * MK] = v3;
    }
}

extern "C" void kernel_launch(void* const* d_in, const int* in_sizes, int n_in,
                              void* d_out, int out_size, void* d_ws, size_t ws_size,
                              hipStream_t stream) {
    const float* new_xyz = (const float*)d_in[0];   // (B,3,M)
    const float* xyz     = (const float*)d_in[1];   // (B,3,N)
    const float* feat    = (const float*)d_in[2];   // (B,C,N)

    const int B = 4;                       // fixed by harness setup
    const int M = in_sizes[0] / (3 * B);   // 2048
    const int N = in_sizes[1] / (3 * B);   // 8192
    const int C = in_sizes[2] / (B * N);   // 128

    const long long sz_with = (long long)B * (C + 6) * M * K_NEIGH;
    const int use_xyz = (out_size == sz_with) ? 1 : 0;

    float* out0 = (float*)d_out;
    float* out1 = out0 + (size_t)B * (use_xyz ? (C + 3) : C) * M * K_NEIGH;

    int* idxb = (int*)d_ws;  // B*M*K ints = 1 MB
    const size_t idx_bytes = (size_t)B * M * K_NEIGH * sizeof(int);

    const bool fast = (B == 4) && (N == NPTS) && (M == MQ) && (C == CCH)
                      && (ws_size >= idx_bytes);

    ball_query_xyz_kernel<<<(B * M) / 4, 256, 0, stream>>>(
        xyz, new_xyz, idxb, out0, out1, N, M, C, use_xyz);

    if (fast) {
        gather_onepass_kernel<<<256, 1024, 0, stream>>>(feat, idxb, out0, use_xyz);
    } else {
        gather_kernel<<<B * (M / 8), 256, 0, stream>>>(xyz, new_xyz, feat, idxb,
                                                       out0, out1, N, M, C, use_xyz);
    }
}